// Round 9
// baseline (260.970 us; speedup 1.0000x reference)
//
#include <hip/hip_runtime.h>
#include <hip/hip_bf16.h>

// StructuralAttention v9: barrier-free, LDS-free attention at 3 waves/SIMD.
//   S_eff = X*M*X^T + 1*v^T (M = Wq^T Wk * scale * log2e), P = exp2(S_eff)
//   O     = (P * V)/rowsum(P) + bv,  V = X*Wv^T  (Vtg precomputed, transposed)
// K0: Mt bf16[128][128] (log2e-folded), w f32[128] (log2e-folded), Wvb bf16.
// K1: per 64-row tile: xb = bf16(x) (global), Vtg[graph][o][k] bf16, vvec = X*w.
//     16 KB LDS, (256,4) — BW-bound, high occupancy.
// K2: 1024 blocks x 256 thr, (256,3) => 3 blocks/CU, 12 waves/CU, ~170 regs/wave
//     (R5's natural allocation), ZERO LDS, ZERO barriers. R7's main-loop math,
//     all MFMA fragments loaded straight from xb/Vtg (L1/L2-hot: 128 KB/graph).

typedef float f32x4 __attribute__((ext_vector_type(4)));
typedef unsigned int u32x2 __attribute__((ext_vector_type(2)));
typedef unsigned int u32x4 __attribute__((ext_vector_type(4)));
typedef short s16x8 __attribute__((ext_vector_type(8)));

#define SCALE 0.088388347648318447f   // 1/sqrt(128)
#define LOG2E 1.4426950408889634f
// d_ws layout
#define WOFF  32768                   // w f32[128]
#define WVB   33280                   // Wvb bf16[128][128]
#define XB    131072                  // xb bf16[131072][128] (33.5 MB)
#define VTG   (XB + 33554432)         // Vtg bf16[512][128][256] (33.5 MB)
#define VVEC  (VTG + 33554432)        // vvec f32[131072] (0.5 MB)

__device__ __forceinline__ unsigned short bf16s(float a) {
    return __builtin_bit_cast(unsigned short, __float2bfloat16(a));  // RNE
}
__device__ __forceinline__ unsigned bf16pk(float a, float b) {
    return (unsigned)bf16s(a) | ((unsigned)bf16s(b) << 16);
}
__device__ __forceinline__ f32x4 mfma32(u32x4 a, u32x4 b, f32x4 c) {
    return __builtin_amdgcn_mfma_f32_16x16x32_bf16(
        __builtin_bit_cast(s16x8, a), __builtin_bit_cast(s16x8, b), c, 0, 0, 0);
}
// K1 LDS tile: bf16[64][128] + XOR swizzle
__device__ __forceinline__ int ks_off(int row, int d) {
    return (row << 8) + ((d << 1) ^ ((row & 15) << 3));
}

// ---------------- K0: Mt (log2e-folded) + w + Wvb -> d_ws ----------------
extern "C" __global__ void __launch_bounds__(256)
sattn_pre(const float* __restrict__ Wq, const float* __restrict__ bq,
          const float* __restrict__ Wk, const float* __restrict__ Wv,
          char* __restrict__ wsb)
{
    const int b = blockIdx.x, t = threadIdx.x;
    if (b < 64) {
        const int row = b * 2 + (t >> 7);   // Mt row = "k-side" feature
        const int a   = t & 127;
        float acc = 0.f;
#pragma unroll 8
        for (int o = 0; o < 128; ++o)
            acc += Wq[o * 128 + a] * Wk[o * 128 + row];
        *(unsigned short*)(wsb + (row << 8) + (a << 1)) = bf16s(acc * SCALE * LOG2E);
    } else if (b == 64) {
        if (t < 128) {
            float acc = 0.f;
#pragma unroll 8
            for (int o = 0; o < 128; ++o)
                acc += bq[o] * Wk[o * 128 + t];
            *(float*)(wsb + WOFF + 4 * t) = acc * SCALE * LOG2E;
        }
    } else {
        const int row = (b - 65) * 2 + (t >> 7);
        const int col = t & 127;
        *(unsigned short*)(wsb + WVB + (row << 8) + (col << 1)) =
            bf16s(Wv[row * 128 + col]);
    }
}

// ---------------- K1: xb + Vtg + vvec (64 node-rows per block) ----------------
extern "C" __global__ void __launch_bounds__(256, 4)
sattn_prep(const float* __restrict__ x, char* __restrict__ wsb)
{
    __shared__ char sm[16384];
    const int t    = threadIdx.x;
    const int lane = t & 63;
    const int wv4  = t >> 6;        // wave 0..3
    const int h    = lane & 15;
    const int g    = lane >> 4;
    const int r0   = blockIdx.x << 6;     // global node base
    const int gid  = r0 >> 8;
    const int kb   = r0 & 255;            // k-base within graph
    const f32x4 Z  = {0.f, 0.f, 0.f, 0.f};

    // stage: each thread 1 row x 32 cols -> xb (global bf16) + LDS tile + vvec
    {
        const int rowl = t >> 2;
        const int ch   = (t & 3) << 5;
        const float* xr = x + (size_t)(r0 + rowl) * 128 + ch;
        const float* wv = (const float*)(wsb + WOFF) + ch;
        f32x4 xa[8];
#pragma unroll
        for (int j = 0; j < 8; ++j) xa[j] = *(const f32x4*)(xr + 4 * j);
        unsigned pk[16];
        float vacc = 0.f;
#pragma unroll
        for (int j = 0; j < 8; ++j) {
            f32x4 wj = *(const f32x4*)(wv + 4 * j);
            vacc += xa[j].x * wj.x + xa[j].y * wj.y + xa[j].z * wj.z + xa[j].w * wj.w;
            pk[2 * j]     = bf16pk(xa[j].x, xa[j].y);
            pk[2 * j + 1] = bf16pk(xa[j].z, xa[j].w);
        }
        char* xbp = wsb + XB + (size_t)(r0 + rowl) * 256 + ch * 2;
#pragma unroll
        for (int m = 0; m < 4; ++m)
            *(u32x4*)(xbp + 16 * m) =
                (u32x4){ pk[4 * m], pk[4 * m + 1], pk[4 * m + 2], pk[4 * m + 3] };
#pragma unroll
        for (int j = 0; j < 8; ++j)
            *(u32x2*)(sm + ks_off(rowl, ch + 4 * j)) = (u32x2){ pk[2 * j], pk[2 * j + 1] };
        vacc += __shfl_xor(vacc, 1);
        vacc += __shfl_xor(vacc, 2);
        if ((t & 3) == 0) *(float*)(wsb + VVEC + (size_t)(r0 + rowl) * 4) = vacc;
    }
    __syncthreads();

    // V^T: wave wv4 -> k-rows 16*wv4..+15, all 128 o; store transposed to Vtg
    u32x2 xk[8];
#pragma unroll
    for (int c = 0; c < 8; ++c)
        xk[c] = *(const u32x2*)(sm + ks_off(16 * wv4 + h, 16 * c + 4 * g));
#pragma unroll
    for (int ot = 0; ot < 8; ++ot) {
        f32x4 D = Z;
#pragma unroll
        for (int c2 = 0; c2 < 4; ++c2) {
            const char* wp = wsb + WVB + ((16 * ot + h) << 8) + ((32 * c2 + 4 * g) << 1);
            u32x2 wlo = *(const u32x2*)wp;
            u32x2 whi = *(const u32x2*)(wp + 32);
            u32x4 B = (u32x4){ wlo.x, wlo.y, whi.x, whi.y };
            u32x4 A = (u32x4){ xk[2 * c2].x, xk[2 * c2].y,
                               xk[2 * c2 + 1].x, xk[2 * c2 + 1].y };
            D = mfma32(A, B, D);    // lane h reg r = V[k=16wv4+4g+r][o=16ot+h]
        }
        *(u32x2*)(wsb + VTG + ((size_t)gid << 16) + ((16 * ot + h) << 9)
                  + ((kb + 16 * wv4 + 4 * g) << 1)) =
            (u32x2){ bf16pk(D.x, D.y), bf16pk(D.z, D.w) };
    }
}

// ---------------- K2: attention, no LDS, no barriers ----------------
extern "C" __global__ void __launch_bounds__(256, 3)
sattn(const float* __restrict__ bv, const char* __restrict__ wsb,
      float* __restrict__ out)
{
    const int t    = threadIdx.x;
    const int lane = t & 63;
    const int wv4  = t >> 6;                      // wave 0..3
    const int h    = lane & 15;
    const int g    = lane >> 4;
    const int b    = blockIdx.x;
    const int gid  = b >> 1;
    const int R0   = gid << 8;
    const int q0   = ((b & 1) << 7) + (wv4 << 5); // wave's 32-q slab
    const f32x4 Z  = {0.f, 0.f, 0.f, 0.f};

    const char*  xbg = wsb + XB + (size_t)R0 * 256;
    const char*  vtg = wsb + VTG + ((size_t)gid << 16);
    const float* vvg = (const float*)(wsb + VVEC) + R0;

    // prologue: own-row X frags -> yf via Mt (global/L2)
    u32x2 yf[8][2];
    {
        u32x2 bx[2][8];
#pragma unroll
        for (int qt = 0; qt < 2; ++qt)
#pragma unroll
            for (int c = 0; c < 8; ++c)
                bx[qt][c] = *(const u32x2*)(xbg + (q0 + 16 * qt + h) * 256
                                            + ((16 * c + 4 * g) << 1));
#pragma unroll
        for (int jt = 0; jt < 8; ++jt) {
            f32x4 a0 = Z, a1 = Z;
#pragma unroll
            for (int c2 = 0; c2 < 4; ++c2) {
                const char* mp = wsb + ((h + 16 * jt) << 8) + ((32 * c2 + 4 * g) << 1);
                u32x2 mlo = *(const u32x2*)mp;
                u32x2 mhi = *(const u32x2*)(mp + 32);
                u32x4 A = (u32x4){ mlo.x, mlo.y, mhi.x, mhi.y };
                u32x4 B0 = (u32x4){ bx[0][2 * c2].x, bx[0][2 * c2].y,
                                    bx[0][2 * c2 + 1].x, bx[0][2 * c2 + 1].y };
                u32x4 B1 = (u32x4){ bx[1][2 * c2].x, bx[1][2 * c2].y,
                                    bx[1][2 * c2 + 1].x, bx[1][2 * c2 + 1].y };
                a0 = mfma32(A, B0, a0);
                a1 = mfma32(A, B1, a1);
            }
            yf[jt][0] = (u32x2){ bf16pk(a0.x, a0.y), bf16pk(a0.z, a0.w) };
            yf[jt][1] = (u32x2){ bf16pk(a1.x, a1.y), bf16pk(a1.z, a1.w) };
        }
    }

    // main loop: S^T = xb*yf ; P = exp2(S+v) (B-frag-ready) ; O^T += Vtg*P
    f32x4 Oacc[8][2];
#pragma unroll
    for (int ot = 0; ot < 8; ++ot) { Oacc[ot][0] = Z; Oacc[ot][1] = Z; }
    float ls0 = 0.f, ls1 = 0.f;

#pragma unroll 2
    for (int kc2 = 0; kc2 < 8; ++kc2) {
        u32x2 pk0[2], pk1[2];
#pragma unroll
        for (int kk = 0; kk < 2; ++kk) {
            const int kc = 2 * kc2 + kk;
            f32x4 a0 = Z, a1 = Z;
#pragma unroll
            for (int c2 = 0; c2 < 4; ++c2) {
                const char* xp = xbg + (16 * kc + h) * 256 + ((32 * c2 + 4 * g) << 1);
                u32x2 xlo = *(const u32x2*)xp;
                u32x2 xhi = *(const u32x2*)(xp + 32);
                u32x4 A = (u32x4){ xlo.x, xlo.y, xhi.x, xhi.y };
                u32x4 B0 = (u32x4){ yf[2 * c2][0].x, yf[2 * c2][0].y,
                                    yf[2 * c2 + 1][0].x, yf[2 * c2 + 1][0].y };
                u32x4 B1 = (u32x4){ yf[2 * c2][1].x, yf[2 * c2][1].y,
                                    yf[2 * c2 + 1][1].x, yf[2 * c2 + 1][1].y };
                a0 = mfma32(A, B0, a0);   // lane h reg r = S[k=16kc+4g+r][q=q0+h]
                a1 = mfma32(A, B1, a1);   // ... q=q0+16+h
            }
            f32x4 vv = *(const f32x4*)(vvg + 16 * kc + 4 * g);
            float e0 = exp2f(a0.x + vv.x), e1 = exp2f(a0.y + vv.y);
            float e2 = exp2f(a0.z + vv.z), e3 = exp2f(a0.w + vv.w);
            float f0 = exp2f(a1.x + vv.x), f1 = exp2f(a1.y + vv.y);
            float f2 = exp2f(a1.z + vv.z), f3 = exp2f(a1.w + vv.w);
            ls0 += e0 + e1 + e2 + e3;
            ls1 += f0 + f1 + f2 + f3;
            pk0[kk] = (u32x2){ bf16pk(e0, e1), bf16pk(e2, e3) };
            pk1[kk] = (u32x2){ bf16pk(f0, f1), bf16pk(f2, f3) };
        }
        // Vt fragment loads (independent of P -> scheduler can hoist over exp)
        u32x2 vl[8], vh[8];
#pragma unroll
        for (int ot = 0; ot < 8; ++ot) {
            const char* vp = vtg + ((16 * ot + h) << 9) + ((32 * kc2 + 4 * g) << 1);
            vl[ot] = *(const u32x2*)vp;
            vh[ot] = *(const u32x2*)(vp + 32);
        }
        u32x4 pa0 = (u32x4){ pk0[0].x, pk0[0].y, pk0[1].x, pk0[1].y };
        u32x4 pa1 = (u32x4){ pk1[0].x, pk1[0].y, pk1[1].x, pk1[1].y };
#pragma unroll
        for (int ot = 0; ot < 8; ++ot) {
            u32x4 A = (u32x4){ vl[ot].x, vl[ot].y, vh[ot].x, vh[ot].y };
            Oacc[ot][0] = mfma32(A, pa0, Oacc[ot][0]);
            Oacc[ot][1] = mfma32(A, pa1, Oacc[ot][1]);
        }
    }
    ls0 += __shfl_xor(ls0, 16); ls0 += __shfl_xor(ls0, 32);
    ls1 += __shfl_xor(ls1, 16); ls1 += __shfl_xor(ls1, 32);
    const float li0 = 1.0f / ls0;   // q = q0 + h
    const float li1 = 1.0f / ls1;   // q = q0 + 16 + h

    // epilogue: O^T store-ready (regs r = 4 contiguous o-cols)
#pragma unroll
    for (int ot = 0; ot < 8; ++ot) {
        f32x4 bvv = *(const f32x4*)(bv + 16 * ot + 4 * g);
        f32x4 r0, r1;
#pragma unroll
        for (int j = 0; j < 4; ++j) {
            r0[j] = Oacc[ot][0][j] * li0 + bvv[j];
            r1[j] = Oacc[ot][1][j] * li1 + bvv[j];
        }
        *(f32x4*)(out + (size_t)(R0 + q0 + h) * 128 + 16 * ot + 4 * g)      = r0;
        *(f32x4*)(out + (size_t)(R0 + q0 + 16 + h) * 128 + 16 * ot + 4 * g) = r1;
    }
}

extern "C" void kernel_launch(void* const* d_in, const int* in_sizes, int n_in,
                              void* d_out, int out_size, void* d_ws, size_t ws_size,
                              hipStream_t stream) {
    const float* x  = (const float*)d_in[0];
    const float* Wq = (const float*)d_in[2];
    const float* bq = (const float*)d_in[3];
    const float* Wk = (const float*)d_in[4];
    const float* Wv = (const float*)d_in[6];
    const float* bv = (const float*)d_in[7];
    float* out = (float*)d_out;
    char* wsb = (char*)d_ws;

    sattn_pre <<<dim3(129),  dim3(256), 0, stream>>>(Wq, bq, Wk, Wv, wsb);
    sattn_prep<<<dim3(2048), dim3(256), 0, stream>>>(x, wsb);
    sattn     <<<dim3(1024), dim3(256), 0, stream>>>(bv, wsb, out);
}